// Round 4
// baseline (217.478 us; speedup 1.0000x reference)
//
#include <hip/hip_runtime.h>

// out[b,o] = sum_f x[b,f] * weight[o,f] * m[b,o,f] + bias[o]
// B=256, O=1024, F=1024, all fp32. m is 1 GiB -> pure HBM stream.
// One wave (64 lanes) per output element; 16 floats/lane as 4x float4.

#define FIN   1024
#define FOUT  1024
#define BATCH 256

__global__ __launch_bounds__(256) void dwa_row_reduce(
    const float* __restrict__ x,     // [BATCH][FIN]
    const float* __restrict__ m,     // [BATCH][FOUT][FIN]
    const float* __restrict__ w,     // [FOUT][FIN]
    const float* __restrict__ bias,  // [FOUT]
    float* __restrict__ out)         // [BATCH][FOUT]
{
    const int gtid = blockIdx.x * blockDim.x + threadIdx.x;
    const int wave = gtid >> 6;          // global wave index = output element
    const int lane = threadIdx.x & 63;

    const int b = wave >> 10;            // / FOUT
    const int o = wave & (FOUT - 1);     // % FOUT

    const float* mrow = m + ((size_t)b * FOUT + (size_t)o) * FIN;
    const float* xrow = x + (size_t)b * FIN;
    const float* wrow = w + (size_t)o * FIN;

    float acc = 0.0f;
#pragma unroll
    for (int c = 0; c < FIN / (64 * 4); ++c) {   // 4 chunks of 256 floats
        const int f = c * 256 + lane * 4;
        const float4 mv = *reinterpret_cast<const float4*>(mrow + f);
        const float4 xv = *reinterpret_cast<const float4*>(xrow + f);
        const float4 wv = *reinterpret_cast<const float4*>(wrow + f);
        acc += mv.x * xv.x * wv.x;
        acc += mv.y * xv.y * wv.y;
        acc += mv.z * xv.z * wv.z;
        acc += mv.w * xv.w * wv.w;
    }

    // 64-lane tree reduction
#pragma unroll
    for (int off = 32; off > 0; off >>= 1)
        acc += __shfl_down(acc, off, 64);

    if (lane == 0)
        out[(size_t)b * FOUT + o] = acc + bias[o];
}

extern "C" void kernel_launch(void* const* d_in, const int* in_sizes, int n_in,
                              void* d_out, int out_size, void* d_ws, size_t ws_size,
                              hipStream_t stream) {
    const float* x    = (const float*)d_in[0];   // [256][1024]
    const float* m    = (const float*)d_in[1];   // [256][1024][1024]
    const float* wgt  = (const float*)d_in[2];   // [1024][1024]
    const float* bias = (const float*)d_in[3];   // [1024]
    float* out = (float*)d_out;                  // [256][1024]

    const int total_waves   = BATCH * FOUT;            // 262144
    const int threads       = 256;                     // 4 waves/block
    const int waves_per_blk = threads / 64;
    const int blocks        = total_waves / waves_per_blk;  // 65536

    dwa_row_reduce<<<blocks, threads, 0, stream>>>(x, m, wgt, bias, out);
}

// Round 5
// 206.735 us; speedup vs baseline: 1.0520x; 1.0520x over previous
//
#include <hip/hip_runtime.h>

// out[b,o] = sum_f x[b,f] * weight[o,f] * m[b,o,f] + bias[o]
// B=256, O=1024, F=1024, fp32. m is 1 GiB, touched once -> HBM-stream bound.
// Persistent waves: each wave owns 32 consecutive rows (same b), x slice
// cached in registers, m loaded nontemporal (no reuse, keep L2 for w/x).

#define FIN   1024
#define FOUT  1024
#define BATCH 256
#define ROWS_PER_WAVE 32

typedef float v4f __attribute__((ext_vector_type(4)));

__global__ __launch_bounds__(256) void dwa_row_reduce(
    const float* __restrict__ x,     // [BATCH][FIN]
    const float* __restrict__ m,     // [BATCH][FOUT][FIN]
    const float* __restrict__ w,     // [FOUT][FIN]
    const float* __restrict__ bias,  // [FOUT]
    float* __restrict__ out)         // [BATCH][FOUT]
{
    const int gtid = blockIdx.x * blockDim.x + threadIdx.x;
    const int wave = gtid >> 6;            // 8192 waves total
    const int lane = threadIdx.x & 63;

    const int row0 = wave * ROWS_PER_WAVE; // first (b,o) row of this wave
    const int b    = row0 >> 10;           // / FOUT  (constant over the 32 rows)
    const int o0   = row0 & (FOUT - 1);    // % FOUT

    // x slice for this wave's f-positions, cached in 16 VGPRs (reused 32x)
    v4f xv[4];
    {
        const float* xrow = x + (size_t)b * FIN;
#pragma unroll
        for (int c = 0; c < 4; ++c)
            xv[c] = *reinterpret_cast<const v4f*>(xrow + c * 256 + lane * 4);
    }

    const float* mrow = m + (size_t)row0 * FIN;
    const float* wrow = w + (size_t)o0 * FIN;

#pragma unroll 2
    for (int r = 0; r < ROWS_PER_WAVE; ++r) {
        float acc = 0.0f;
#pragma unroll
        for (int c = 0; c < 4; ++c) {
            const int f = c * 256 + lane * 4;
            const v4f mv = __builtin_nontemporal_load(
                                reinterpret_cast<const v4f*>(mrow + f));
            const v4f wv = *reinterpret_cast<const v4f*>(wrow + f);
            acc += xv[c].x * wv.x * mv.x;
            acc += xv[c].y * wv.y * mv.y;
            acc += xv[c].z * wv.z * mv.z;
            acc += xv[c].w * wv.w * mv.w;
        }
        // 64-lane tree reduction
#pragma unroll
        for (int off = 32; off > 0; off >>= 1)
            acc += __shfl_down(acc, off, 64);

        if (lane == 0)
            out[row0 + r] = acc + bias[o0 + r];

        mrow += FIN;
        wrow += FIN;
    }
}

extern "C" void kernel_launch(void* const* d_in, const int* in_sizes, int n_in,
                              void* d_out, int out_size, void* d_ws, size_t ws_size,
                              hipStream_t stream) {
    const float* x    = (const float*)d_in[0];   // [256][1024]
    const float* m    = (const float*)d_in[1];   // [256][1024][1024]
    const float* wgt  = (const float*)d_in[2];   // [1024][1024]
    const float* bias = (const float*)d_in[3];   // [1024]
    float* out = (float*)d_out;                  // [256][1024]

    const int total_rows = BATCH * FOUT;                     // 262144
    const int waves      = total_rows / ROWS_PER_WAVE;       // 8192
    const int threads    = 256;                              // 4 waves/block
    const int blocks     = waves / (threads / 64);           // 2048

    dwa_row_reduce<<<blocks, threads, 0, stream>>>(x, m, wgt, bias, out);
}

// Round 6
// 182.594 us; speedup vs baseline: 1.1910x; 1.1322x over previous
//
#include <hip/hip_runtime.h>

// out[b,o] = sum_f x[b,f] * weight[o,f] * m[b,o,f] + bias[o]
// B=256, O=1024, F=1024, fp32. m is 1 GiB, touched once -> HBM-stream bound.
// R6 change (single variable): the 4 waves of a block now share ONE w-slice
// (same 32-row o-group, 4 different batches) -> 3/4 of w loads become L1
// hits, halving VMEM miss traffic next to the m stream. m stays nontemporal.

#define FIN   1024
#define FOUT  1024
#define BATCH 256
#define ROWS_PER_WAVE 32   // one o-group
#define OGROUPS (FOUT / ROWS_PER_WAVE)   // 32

typedef float v4f __attribute__((ext_vector_type(4)));

__global__ __launch_bounds__(256) void dwa_row_reduce(
    const float* __restrict__ x,     // [BATCH][FIN]
    const float* __restrict__ m,     // [BATCH][FOUT][FIN]
    const float* __restrict__ w,     // [FOUT][FIN]
    const float* __restrict__ bias,  // [FOUT]
    float* __restrict__ out)         // [BATCH][FOUT]
{
    const int k    = blockIdx.x;            // 2048 blocks
    const int og   = k & (OGROUPS - 1);     // o-group, shared by all 4 waves
    const int bq   = k >> 5;                // batch quad (0..63)
    const int wv   = threadIdx.x >> 6;      // wave in block (0..3)
    const int lane = threadIdx.x & 63;

    const int b  = bq * 4 + wv;             // this wave's batch
    const int o0 = og * ROWS_PER_WAVE;      // first output row (same per block)

    // x slice for this wave's f-positions, cached in 16 VGPRs (reused 32x)
    v4f xv[4];
    {
        const float* xrow = x + (size_t)b * FIN;
#pragma unroll
        for (int c = 0; c < 4; ++c)
            xv[c] = *reinterpret_cast<const v4f*>(xrow + c * 256 + lane * 4);
    }

    const float* mrow = m + ((size_t)b * FOUT + (size_t)o0) * FIN;
    const float* wrow = w + (size_t)o0 * FIN;   // identical across the 4 waves

#pragma unroll 2
    for (int r = 0; r < ROWS_PER_WAVE; ++r) {
        float a0 = 0.0f, a1 = 0.0f, a2 = 0.0f, a3 = 0.0f;
#pragma unroll
        for (int c = 0; c < 4; ++c) {
            const int f = c * 256 + lane * 4;
            const v4f mv = __builtin_nontemporal_load(
                                reinterpret_cast<const v4f*>(mrow + f));
            const v4f wv4 = *reinterpret_cast<const v4f*>(wrow + f);
            float p;
            p = xv[c].x * wv4.x; a0 += p * mv.x;
            p = xv[c].y * wv4.y; a1 += p * mv.y;
            p = xv[c].z * wv4.z; a2 += p * mv.z;
            p = xv[c].w * wv4.w; a3 += p * mv.w;
        }
        float acc = (a0 + a1) + (a2 + a3);

        // 64-lane tree reduction
#pragma unroll
        for (int off = 32; off > 0; off >>= 1)
            acc += __shfl_down(acc, off, 64);

        if (lane == 0)
            out[(size_t)b * FOUT + o0 + r] = acc + bias[o0 + r];

        mrow += FIN;
        wrow += FIN;
    }
}

extern "C" void kernel_launch(void* const* d_in, const int* in_sizes, int n_in,
                              void* d_out, int out_size, void* d_ws, size_t ws_size,
                              hipStream_t stream) {
    const float* x    = (const float*)d_in[0];   // [256][1024]
    const float* m    = (const float*)d_in[1];   // [256][1024][1024]
    const float* wgt  = (const float*)d_in[2];   // [1024][1024]
    const float* bias = (const float*)d_in[3];   // [1024]
    float* out = (float*)d_out;                  // [256][1024]

    const int blocks  = (BATCH / 4) * OGROUPS;   // 64 * 32 = 2048
    const int threads = 256;                     // 4 waves/block

    dwa_row_reduce<<<blocks, threads, 0, stream>>>(x, m, wgt, bias, out);
}